// Round 6
// baseline (335.090 us; speedup 1.0000x reference)
//
#include <hip/hip_runtime.h>
#include <math.h>

#define PP 8192
#define DD 4096
#define NTOT 32768           // B * P
#define K_LOW 29490          // floor(0.9 * (NTOT-1))
#define NBINS 8192           // bucket = bits(|a|) >> 18
#define SCALE 1048576.0f     // 2^20 fixed-point for spmv accumulation
#define INV_SCALE (1.0f / 1048576.0f)
#define MSCALE 262144.0f     // 2^18 fixed-point for mean-sum accumulation
#define INV_MSCALE (1.0f / 262144.0f)
#define LIST_CAP 3072
#define NBLK 256
#define NTHR 512

__device__ __forceinline__ float dot4(float4 w, float4 v) {
  return fmaf(w.x, v.x, fmaf(w.y, v.y, fmaf(w.z, v.z, w.w * v.w)));
}

// LDS reused across phases (64 KB total, 1 block/CU).
struct ThrShared {
  unsigned h[NBINS];        // 32 KB
  unsigned list1[LIST_CAP]; // 12 KB
  unsigned list2[LIST_CAP]; // 12 KB
  unsigned scan[NTHR];      // 2 KB
  unsigned n1, n2, b1, r1, b2, r2, vlo, vhi;
};
struct SpmvShared {
  float st[PP];             // 32 KB
  int   rc[PP];             // 32 KB
};
union FusedShared {
  ThrShared t;
  SpmvShared s;
};

// Device-scope grid barrier: every thread fences (release), thread 0 arrives
// and spins on a device-scope RMW until `target` arrivals, then acquire fence.
// Safe: grid 256 blocks x 512 thr / 64 KB LDS -> whole grid co-resident.
__device__ __forceinline__ void grid_barrier(unsigned* cnt, unsigned target) {
  __threadfence();
  __syncthreads();
  if (threadIdx.x == 0) {
    atomicAdd(cnt, 1u);
    while (atomicAdd(cnt, 0u) < target) __builtin_amdgcn_s_sleep(2);
  }
  __syncthreads();
  __threadfence();
}

__global__ __launch_bounds__(NTHR) void fused_kernel(
    const float* __restrict__ x, const float* __restrict__ W,
    const float* __restrict__ bias, const float* __restrict__ vals,
    const int* __restrict__ rows, const int* __restrict__ cols,
    const float* __restrict__ sstate, float* __restrict__ a,
    int* __restrict__ rec, int* __restrict__ acc, unsigned* __restrict__ bar,
    float* __restrict__ out, int nc) {
  __shared__ FusedShared sh;
  const int tid = threadIdx.x;
  const int blk = blockIdx.x;
  const int lane = tid & 63;
  const int wave = tid >> 6;

  // ---------- phase 0a: zero rec + acc ----------
  {
    const int g = blk * NTHR + tid;
    if (g < PP) rec[g] = 0;
    if (g >= PP && g < PP + 4) acc[g - PP] = 0;
  }

  // ---------- phase 0b: gemm  a = x @ W^T + b ----------
  // 32 rows/block, 4 rows/wave; same per-(row,batch) fp order as prior rounds.
  {
    const int p0 = blk * 32 + wave * 4;
    const float4* __restrict__ Wr0 = (const float4*)(W + (size_t)p0 * DD);
    const float4* __restrict__ Wr1 = (const float4*)(W + (size_t)(p0 + 1) * DD);
    const float4* __restrict__ Wr2 = (const float4*)(W + (size_t)(p0 + 2) * DD);
    const float4* __restrict__ Wr3 = (const float4*)(W + (size_t)(p0 + 3) * DD);
    const float4* __restrict__ x4 = (const float4*)x;
    double accd[4][4];
    #pragma unroll
    for (int r = 0; r < 4; ++r)
      #pragma unroll
      for (int b = 0; b < 4; ++b) accd[r][b] = 0.0;
    #pragma unroll 2
    for (int k = 0; k < 16; ++k) {
      const int i = lane + k * 64;
      float4 w0 = Wr0[i];
      float4 w1 = Wr1[i];
      float4 w2 = Wr2[i];
      float4 w3 = Wr3[i];
      float4 v0 = x4[i];
      float4 v1 = x4[1024 + i];
      float4 v2 = x4[2048 + i];
      float4 v3 = x4[3072 + i];
      accd[0][0] += (double)dot4(w0, v0);
      accd[0][1] += (double)dot4(w0, v1);
      accd[0][2] += (double)dot4(w0, v2);
      accd[0][3] += (double)dot4(w0, v3);
      accd[1][0] += (double)dot4(w1, v0);
      accd[1][1] += (double)dot4(w1, v1);
      accd[1][2] += (double)dot4(w1, v2);
      accd[1][3] += (double)dot4(w1, v3);
      accd[2][0] += (double)dot4(w2, v0);
      accd[2][1] += (double)dot4(w2, v1);
      accd[2][2] += (double)dot4(w2, v2);
      accd[2][3] += (double)dot4(w2, v3);
      accd[3][0] += (double)dot4(w3, v0);
      accd[3][1] += (double)dot4(w3, v1);
      accd[3][2] += (double)dot4(w3, v2);
      accd[3][3] += (double)dot4(w3, v3);
    }
    #pragma unroll
    for (int r = 0; r < 4; ++r)
      #pragma unroll
      for (int b = 0; b < 4; ++b)
        #pragma unroll
        for (int off = 32; off > 0; off >>= 1)
          accd[r][b] += __shfl_down(accd[r][b], off);
    if (lane == 0) {
      #pragma unroll
      for (int r = 0; r < 4; ++r) {
        float bp = bias[p0 + r];
        #pragma unroll
        for (int b = 0; b < 4; ++b) a[b * PP + p0 + r] = (float)accd[r][b] + bp;
      }
    }
  }

  // ---------- phase 0c: warm this block's COO slice into L2/L3 ----------
  const int quads = nc >> 2;
  const int per = (quads + NBLK - 1) / NBLK;
  const int lo = blk * per;
  const int hi = min(lo + per, quads);
  {
    const float4* __restrict__ v4 = (const float4*)vals;
    const int4* __restrict__ r4 = (const int4*)rows;
    const int4* __restrict__ c4 = (const int4*)cols;
    float fs = 0.0f;
    int is = 0;
    for (int i = lo + tid; i < hi; i += NTHR) {
      float4 v = v4[i];
      int4 r = r4[i];
      int4 c = c4[i];
      fs += v.x + v.y + v.z + v.w;
      is += r.x + r.y + r.z + r.w + c.x + c.y + c.z + c.w;
    }
    asm volatile("" :: "v"(fs), "v"(is));  // keep loads live
  }

  grid_barrier(bar, NBLK);  // a complete, rec/acc zeroed, COO warm

  // ---------- phase 1: exact 0.9-quantile (redundant per block) ----------
  float thr_v;
  {
    for (int j = tid; j < NBINS; j += NTHR) sh.t.h[j] = 0u;
    if (tid == 0) { sh.t.n1 = 0; sh.t.n2 = 0; }
    __syncthreads();
    for (int i = tid; i < NTOT; i += NTHR)
      atomicAdd(&sh.t.h[__float_as_uint(fabsf(a[i])) >> 18], 1u);
    __syncthreads();
    unsigned bins[16];
    unsigned part = 0;
    #pragma unroll
    for (int j = 0; j < 16; ++j) {
      bins[j] = sh.t.h[tid * 16 + j];
      part += bins[j];
    }
    sh.t.scan[tid] = part;
    __syncthreads();
    for (int off = 1; off < NTHR; off <<= 1) {
      unsigned vv = (tid >= off) ? sh.t.scan[tid - off] : 0u;
      __syncthreads();
      sh.t.scan[tid] += vv;
      __syncthreads();
    }
    const unsigned incl = sh.t.scan[tid];
    const unsigned excl = incl - part;
    if (excl <= (unsigned)K_LOW && (unsigned)K_LOW < incl) {
      unsigned r = (unsigned)K_LOW - excl, cum = 0;
      #pragma unroll
      for (int j = 0; j < 16; ++j) {
        if (cum + bins[j] > r) { sh.t.b1 = tid * 16 + j; sh.t.r1 = r - cum; break; }
        cum += bins[j];
      }
    }
    if (excl <= (unsigned)(K_LOW + 1) && (unsigned)(K_LOW + 1) < incl) {
      unsigned r = (unsigned)(K_LOW + 1) - excl, cum = 0;
      #pragma unroll
      for (int j = 0; j < 16; ++j) {
        if (cum + bins[j] > r) { sh.t.b2 = tid * 16 + j; sh.t.r2 = r - cum; break; }
        cum += bins[j];
      }
    }
    __syncthreads();
    const unsigned b1 = sh.t.b1, r1 = sh.t.r1, b2 = sh.t.b2, r2 = sh.t.r2;
    for (int i = tid; i < NTOT; i += NTHR) {
      unsigned u = __float_as_uint(fabsf(a[i]));
      unsigned bk = u >> 18;
      if (bk == b1) {
        unsigned idx = atomicAdd(&sh.t.n1, 1u);
        if (idx < LIST_CAP) sh.t.list1[idx] = u;
      } else if (bk == b2) {
        unsigned idx = atomicAdd(&sh.t.n2, 1u);
        if (idx < LIST_CAP) sh.t.list2[idx] = u;
      }
    }
    __syncthreads();
    const unsigned m1 = min(sh.t.n1, (unsigned)LIST_CAP);
    const unsigned m2 = min(sh.t.n2, (unsigned)LIST_CAP);
    for (unsigned i = tid; i < m1; i += NTHR) {
      unsigned ui = sh.t.list1[i];
      unsigned ltc = 0, eqb = 0;
      for (unsigned j = 0; j < m1; ++j) {
        unsigned uj = sh.t.list1[j];
        ltc += (uj < ui) ? 1u : 0u;
        eqb += ((uj == ui) && (j < i)) ? 1u : 0u;
      }
      unsigned rk = ltc + eqb;
      if (rk == r1) sh.t.vlo = ui;
      if (b2 == b1 && rk == r2) sh.t.vhi = ui;
    }
    if (b2 != b1) {
      for (unsigned i = tid; i < m2; i += NTHR) {
        unsigned ui = sh.t.list2[i];
        unsigned ltc = 0, eqb = 0;
        for (unsigned j = 0; j < m2; ++j) {
          unsigned uj = sh.t.list2[j];
          ltc += (uj < ui) ? 1u : 0u;
          eqb += ((uj == ui) && (j < i)) ? 1u : 0u;
        }
        if (ltc + eqb == r2) sh.t.vhi = ui;
      }
    }
    __syncthreads();
    const double dlo = (double)__uint_as_float(sh.t.vlo);
    const double dhi = (double)__uint_as_float(sh.t.vhi);
    const double idxq = 0.9 * (double)(NTOT - 1);
    const double gq = idxq - floor(idxq);
    thr_v = (float)(dlo + gq * (dhi - dlo));
    __syncthreads();  // done with thr-phase LDS before union reuse
  }

  // ---------- phase 2: COO SpMV (int fixed-point LDS accum) ----------
  {
    for (int i = tid; i < PP; i += NTHR) {
      float a0 = a[i];
      sh.s.st[i] = (fabsf(a0) > thr_v) ? a0 : 0.9f * sstate[i];
      sh.s.rc[i] = 0;
    }
    __syncthreads();
    const float4* __restrict__ v4 = (const float4*)vals;
    const int4* __restrict__ r4 = (const int4*)rows;
    const int4* __restrict__ c4 = (const int4*)cols;
    for (int i = lo + tid; i < hi; i += NTHR) {
      float4 v = v4[i];
      int4 r = r4[i];
      int4 c = c4[i];
      atomicAdd((unsigned*)&sh.s.rc[r.x], (unsigned)__float2int_rn(v.x * sh.s.st[c.x] * SCALE));
      atomicAdd((unsigned*)&sh.s.rc[r.y], (unsigned)__float2int_rn(v.y * sh.s.st[c.y] * SCALE));
      atomicAdd((unsigned*)&sh.s.rc[r.z], (unsigned)__float2int_rn(v.z * sh.s.st[c.z] * SCALE));
      atomicAdd((unsigned*)&sh.s.rc[r.w], (unsigned)__float2int_rn(v.w * sh.s.st[c.w] * SCALE));
    }
    if (blk == 0 && tid < (nc - (quads << 2))) {
      int i = (quads << 2) + tid;
      atomicAdd((unsigned*)&sh.s.rc[rows[i]],
                (unsigned)__float2int_rn(vals[i] * sh.s.st[cols[i]] * SCALE));
    }
    __syncthreads();
    for (int i = tid; i < PP; i += NTHR)
      atomicAdd((unsigned*)&rec[i], (unsigned)sh.s.rc[i]);
  }

  grid_barrier(bar, 2u * NBLK);  // rec complete

  // ---------- phase 3: GELU + masked scalar partials ----------
  if (blk < 16) {
    const int p = blk * NTHR + tid;
    float r = (float)rec[p] * INV_SCALE;
    float a0 = a[p];
    bool m = fabsf(a0) > thr_v;
    float st = m ? a0 : 0.9f * sstate[p];
    float v = st + 0.1f * r;
    float ns = 0.5f * v * (1.0f + erff(v * 0.70710678118654752440f));
    out[p] = ns;
    float lsum = m ? ns : 0.0f;
    unsigned lcnt = m ? 1u : 0u;
    #pragma unroll
    for (int off = 32; off > 0; off >>= 1) {
      lsum += __shfl_down(lsum, off);
      lcnt += __shfl_down(lcnt, off);
    }
    if (lane == 0) {
      atomicAdd((unsigned*)&acc[0], (unsigned)__float2int_rn(lsum * MSCALE));
      atomicAdd((unsigned*)&acc[1], lcnt);
    }
  }

  grid_barrier(bar, 3u * NBLK);  // acc complete

  if (blk == 0 && tid == 0) {
    int sfix = (int)atomicAdd((unsigned*)&acc[0], 0u);
    int cnt = (int)atomicAdd((unsigned*)&acc[1], 0u);
    out[PP] = (float)cnt;
    out[PP + 1] = (cnt > 0) ? ((float)sfix * INV_MSCALE / (float)cnt) : 0.0f;
  }
}

extern "C" void kernel_launch(void* const* d_in, const int* in_sizes, int n_in,
                              void* d_out, int out_size, void* d_ws, size_t ws_size,
                              hipStream_t stream) {
  const float* x      = (const float*)d_in[0];
  const float* W      = (const float*)d_in[1];
  const float* bias   = (const float*)d_in[2];
  const float* vals   = (const float*)d_in[3];
  const float* sstate = (const float*)d_in[4];
  const int*   rows   = (const int*)d_in[5];
  const int*   cols   = (const int*)d_in[6];
  const int    nc     = in_sizes[3];
  float* out = (float*)d_out;
  float* ws  = (float*)d_ws;

  float*    a   = ws;                          // 32768 floats
  int*      rec = (int*)(ws + 32768);          // 8192 ints
  int*      acc = (int*)(ws + 32768 + PP);     // 4 ints
  unsigned* bar = (unsigned*)(ws + 32768 + PP + 4);  // 1 uint (barrier counter)

  hipMemsetAsync(bar, 0, 4 * sizeof(unsigned), stream);
  fused_kernel<<<NBLK, NTHR, 0, stream>>>(x, W, bias, vals, rows, cols, sstate,
                                          a, rec, acc, bar, out, nc);
}

// Round 7
// 162.875 us; speedup vs baseline: 2.0573x; 2.0573x over previous
//
#include <hip/hip_runtime.h>
#include <math.h>

#define PP 8192
#define DD 4096
#define NTOT 32768           // B * P
#define K_LOW 29490          // floor(0.9 * (NTOT-1))
#define NBINS 8192           // bucket = bits(|a|) >> 18
#define SCALE 1048576.0f     // 2^20 fixed-point for spmv accumulation
#define INV_SCALE (1.0f / 1048576.0f)
#define MSCALE 262144.0f     // 2^18 fixed-point for mean-sum accumulation
#define INV_MSCALE (1.0f / 262144.0f)
#define LIST_CAP 3072

__device__ __forceinline__ float dot4(float4 w, float4 v) {
  return fmaf(w.x, v.x, fmaf(w.y, v.y, fmaf(w.z, v.z, w.w * v.w)));
}

// ---------------- Kernel 1: a = x @ W^T + b, fused hist atomics ----------------
// 1024 blocks x 256 thr; wave w handles rows p0=blk*8+2w, p0+1. No LDS ->
// 4 blocks/CU (16 waves/CU) for latency hiding. hist pre-zeroed by memset.
__global__ __launch_bounds__(256, 4) void gemm_kernel(const float* __restrict__ x,
                                                      const float* __restrict__ W,
                                                      const float* __restrict__ bias,
                                                      float* __restrict__ a,
                                                      unsigned* __restrict__ hist) {
  const int wave = threadIdx.x >> 6;
  const int lane = threadIdx.x & 63;
  const int p0 = blockIdx.x * 8 + wave * 2;
  const float4* __restrict__ W0 = (const float4*)(W + (size_t)p0 * DD);
  const float4* __restrict__ W1 = W0 + (DD / 4);
  const float4* __restrict__ x4 = (const float4*)x;
  double a00 = 0.0, a01 = 0.0, a02 = 0.0, a03 = 0.0;
  double a10 = 0.0, a11 = 0.0, a12 = 0.0, a13 = 0.0;
  #pragma unroll 4
  for (int k = 0; k < 16; ++k) {
    const int i = lane + k * 64;
    float4 w0 = W0[i];
    float4 w1 = W1[i];
    float4 v0 = x4[i];
    float4 v1 = x4[1024 + i];
    float4 v2 = x4[2048 + i];
    float4 v3 = x4[3072 + i];
    a00 += (double)dot4(w0, v0);
    a01 += (double)dot4(w0, v1);
    a02 += (double)dot4(w0, v2);
    a03 += (double)dot4(w0, v3);
    a10 += (double)dot4(w1, v0);
    a11 += (double)dot4(w1, v1);
    a12 += (double)dot4(w1, v2);
    a13 += (double)dot4(w1, v3);
  }
  #pragma unroll
  for (int off = 32; off > 0; off >>= 1) {
    a00 += __shfl_down(a00, off);
    a01 += __shfl_down(a01, off);
    a02 += __shfl_down(a02, off);
    a03 += __shfl_down(a03, off);
    a10 += __shfl_down(a10, off);
    a11 += __shfl_down(a11, off);
    a12 += __shfl_down(a12, off);
    a13 += __shfl_down(a13, off);
  }
  if (lane == 0) {
    float b0 = bias[p0];
    float b1 = bias[p0 + 1];
    float r00 = (float)a00 + b0;
    float r01 = (float)a01 + b0;
    float r02 = (float)a02 + b0;
    float r03 = (float)a03 + b0;
    float r10 = (float)a10 + b1;
    float r11 = (float)a11 + b1;
    float r12 = (float)a12 + b1;
    float r13 = (float)a13 + b1;
    a[0 * PP + p0] = r00;
    a[1 * PP + p0] = r01;
    a[2 * PP + p0] = r02;
    a[3 * PP + p0] = r03;
    a[0 * PP + p0 + 1] = r10;
    a[1 * PP + p0 + 1] = r11;
    a[2 * PP + p0 + 1] = r12;
    a[3 * PP + p0 + 1] = r13;
    atomicAdd(&hist[__float_as_uint(fabsf(r00)) >> 18], 1u);
    atomicAdd(&hist[__float_as_uint(fabsf(r01)) >> 18], 1u);
    atomicAdd(&hist[__float_as_uint(fabsf(r02)) >> 18], 1u);
    atomicAdd(&hist[__float_as_uint(fabsf(r03)) >> 18], 1u);
    atomicAdd(&hist[__float_as_uint(fabsf(r10)) >> 18], 1u);
    atomicAdd(&hist[__float_as_uint(fabsf(r11)) >> 18], 1u);
    atomicAdd(&hist[__float_as_uint(fabsf(r12)) >> 18], 1u);
    atomicAdd(&hist[__float_as_uint(fabsf(r13)) >> 18], 1u);
  }
}

// ---------------- Kernel 2: exact 0.9-quantile from prebuilt histogram ----------------
__global__ __launch_bounds__(1024) void thr_kernel(const float* __restrict__ a,
                                                   const unsigned* __restrict__ hist,
                                                   float* __restrict__ thr) {
  __shared__ unsigned scan[1024];
  __shared__ unsigned list1[LIST_CAP];
  __shared__ unsigned list2[LIST_CAP];
  __shared__ unsigned s_n1, s_n2;
  __shared__ unsigned s_b1, s_r1, s_b2, s_r2;
  __shared__ unsigned s_vlo, s_vhi;
  const int tid = threadIdx.x;
  const uint4* h4 = (const uint4*)hist;
  uint4 q0 = h4[tid * 2];
  uint4 q1 = h4[tid * 2 + 1];
  unsigned part = q0.x + q0.y + q0.z + q0.w + q1.x + q1.y + q1.z + q1.w;
  scan[tid] = part;
  if (tid == 0) { s_n1 = 0; s_n2 = 0; }
  __syncthreads();
  for (int off = 1; off < 1024; off <<= 1) {
    unsigned v = (tid >= off) ? scan[tid - off] : 0u;
    __syncthreads();
    scan[tid] += v;
    __syncthreads();
  }
  const unsigned incl = scan[tid];
  const unsigned excl = incl - part;
  unsigned bins[8] = {q0.x, q0.y, q0.z, q0.w, q1.x, q1.y, q1.z, q1.w};
  if (excl <= (unsigned)K_LOW && (unsigned)K_LOW < incl) {
    unsigned r = (unsigned)K_LOW - excl, cum = 0;
    #pragma unroll
    for (int j = 0; j < 8; ++j) {
      if (cum + bins[j] > r) { s_b1 = tid * 8 + j; s_r1 = r - cum; break; }
      cum += bins[j];
    }
  }
  if (excl <= (unsigned)(K_LOW + 1) && (unsigned)(K_LOW + 1) < incl) {
    unsigned r = (unsigned)(K_LOW + 1) - excl, cum = 0;
    #pragma unroll
    for (int j = 0; j < 8; ++j) {
      if (cum + bins[j] > r) { s_b2 = tid * 8 + j; s_r2 = r - cum; break; }
      cum += bins[j];
    }
  }
  __syncthreads();
  const unsigned b1 = s_b1, r1 = s_r1, b2 = s_b2, r2 = s_r2;
  for (int i = tid; i < NTOT; i += 1024) {
    unsigned u = __float_as_uint(fabsf(a[i]));
    unsigned bk = u >> 18;
    if (bk == b1) {
      unsigned idx = atomicAdd(&s_n1, 1u);
      if (idx < LIST_CAP) list1[idx] = u;
    } else if (bk == b2) {
      unsigned idx = atomicAdd(&s_n2, 1u);
      if (idx < LIST_CAP) list2[idx] = u;
    }
  }
  __syncthreads();
  const unsigned m1 = min(s_n1, (unsigned)LIST_CAP);
  const unsigned m2 = min(s_n2, (unsigned)LIST_CAP);
  for (unsigned i = tid; i < m1; i += 1024) {
    unsigned ui = list1[i];
    unsigned ltc = 0, eqb = 0;
    for (unsigned j = 0; j < m1; ++j) {
      unsigned uj = list1[j];
      ltc += (uj < ui) ? 1u : 0u;
      eqb += ((uj == ui) && (j < i)) ? 1u : 0u;
    }
    unsigned rk = ltc + eqb;
    if (rk == r1) s_vlo = ui;
    if (b2 == b1 && rk == r2) s_vhi = ui;
  }
  if (b2 != b1) {
    for (unsigned i = tid; i < m2; i += 1024) {
      unsigned ui = list2[i];
      unsigned ltc = 0, eqb = 0;
      for (unsigned j = 0; j < m2; ++j) {
        unsigned uj = list2[j];
        ltc += (uj < ui) ? 1u : 0u;
        eqb += ((uj == ui) && (j < i)) ? 1u : 0u;
      }
      if (ltc + eqb == r2) s_vhi = ui;
    }
  }
  __syncthreads();
  if (tid == 0) {
    double dlo = (double)__uint_as_float(s_vlo);
    double dhi = (double)__uint_as_float(s_vhi);
    double idx = 0.9 * (double)(NTOT - 1);
    double g = idx - floor(idx);
    thr[0] = (float)(dlo + g * (dhi - dlo));
  }
}

// ---------------- Kernel 3: COO SpMV, int fixed-point LDS accum ----------------
__global__ __launch_bounds__(1024) void spmv_kernel(const float* __restrict__ vals,
                                                    const int* __restrict__ rows,
                                                    const int* __restrict__ cols,
                                                    const float* __restrict__ a,
                                                    const float* __restrict__ thr,
                                                    const float* __restrict__ sstate,
                                                    int* __restrict__ rec,
                                                    int nc) {
  __shared__ float s_state[PP];
  __shared__ int s_rec[PP];
  const int tid = threadIdx.x;
  const float t = thr[0];
  for (int i = tid; i < PP; i += 1024) {
    float a0 = a[i];
    s_state[i] = (fabsf(a0) > t) ? a0 : 0.9f * sstate[i];
    s_rec[i] = 0;
  }
  __syncthreads();
  const int n4 = nc >> 2;
  const int stride = gridDim.x * 1024;
  const float4* __restrict__ v4 = (const float4*)vals;
  const int4* __restrict__ r4 = (const int4*)rows;
  const int4* __restrict__ c4 = (const int4*)cols;
  for (int i = blockIdx.x * 1024 + tid; i < n4; i += stride) {
    float4 v = v4[i];
    int4 r = r4[i];
    int4 c = c4[i];
    atomicAdd((unsigned*)&s_rec[r.x], (unsigned)__float2int_rn(v.x * s_state[c.x] * SCALE));
    atomicAdd((unsigned*)&s_rec[r.y], (unsigned)__float2int_rn(v.y * s_state[c.y] * SCALE));
    atomicAdd((unsigned*)&s_rec[r.z], (unsigned)__float2int_rn(v.z * s_state[c.z] * SCALE));
    atomicAdd((unsigned*)&s_rec[r.w], (unsigned)__float2int_rn(v.w * s_state[c.w] * SCALE));
  }
  if (blockIdx.x == 0 && tid < (nc - (n4 << 2))) {
    int i = (n4 << 2) + tid;
    atomicAdd((unsigned*)&s_rec[rows[i]],
              (unsigned)__float2int_rn(vals[i] * s_state[cols[i]] * SCALE));
  }
  __syncthreads();
  for (int i = tid; i < PP; i += 1024)
    atomicAdd((unsigned*)&rec[i], (unsigned)s_rec[i]);
}

// ---------------- Kernel 4: GELU + fused scalars (last-block completion) ----------------
__global__ __launch_bounds__(256) void finalize_kernel(const int* __restrict__ rec,
                                                       const float* __restrict__ a,
                                                       const float* __restrict__ thr,
                                                       const float* __restrict__ sstate,
                                                       float* __restrict__ out,
                                                       int* __restrict__ acc) {
  __shared__ float wsum[4];
  __shared__ unsigned wcnt[4];
  const int p = blockIdx.x * 256 + threadIdx.x;
  const float t = thr[0];
  float r = (float)rec[p] * INV_SCALE;
  float a0 = a[p];
  bool m = fabsf(a0) > t;
  float st = m ? a0 : 0.9f * sstate[p];
  float v = st + 0.1f * r;
  float ns = 0.5f * v * (1.0f + erff(v * 0.70710678118654752440f));
  out[p] = ns;
  float lsum = m ? ns : 0.0f;
  unsigned lcnt = m ? 1u : 0u;
  #pragma unroll
  for (int off = 32; off > 0; off >>= 1) {
    lsum += __shfl_down(lsum, off);
    lcnt += __shfl_down(lcnt, off);
  }
  const int lane = threadIdx.x & 63;
  const int wid = threadIdx.x >> 6;
  if (lane == 0) { wsum[wid] = lsum; wcnt[wid] = lcnt; }
  __syncthreads();
  if (threadIdx.x == 0) {
    float bsum = wsum[0] + wsum[1] + wsum[2] + wsum[3];
    unsigned bcnt = wcnt[0] + wcnt[1] + wcnt[2] + wcnt[3];
    atomicAdd((unsigned*)&acc[0], (unsigned)__float2int_rn(bsum * MSCALE));
    atomicAdd((unsigned*)&acc[1], bcnt);
    __threadfence();
    unsigned d = atomicAdd((unsigned*)&acc[2], 1u);
    if (d == (unsigned)(gridDim.x - 1)) {
      int sfix = (int)atomicAdd((unsigned*)&acc[0], 0u);
      int cnt = (int)atomicAdd((unsigned*)&acc[1], 0u);
      out[PP] = (float)cnt;
      out[PP + 1] = (cnt > 0) ? ((float)sfix * INV_MSCALE / (float)cnt) : 0.0f;
    }
  }
}

extern "C" void kernel_launch(void* const* d_in, const int* in_sizes, int n_in,
                              void* d_out, int out_size, void* d_ws, size_t ws_size,
                              hipStream_t stream) {
  const float* x      = (const float*)d_in[0];
  const float* W      = (const float*)d_in[1];
  const float* bias   = (const float*)d_in[2];
  const float* vals   = (const float*)d_in[3];
  const float* sstate = (const float*)d_in[4];
  const int*   rows   = (const int*)d_in[5];
  const int*   cols   = (const int*)d_in[6];
  const int    nc     = in_sizes[3];
  float* out = (float*)d_out;
  float* ws  = (float*)d_ws;

  float*    a    = ws;                            // 32768 floats
  float*    thr  = ws + 32768;                    // 16 floats
  unsigned* hist = (unsigned*)(ws + 32784);       // 8192 bins
  int*      rec  = (int*)(ws + 32784 + NBINS);    // 8192 ints
  int*      acc  = (int*)(ws + 32784 + NBINS + PP); // 4 ints

  // zero hist + rec + acc in one contiguous memset (stream-ordered, graph-safe)
  hipMemsetAsync(hist, 0, (NBINS + PP + 4) * sizeof(unsigned), stream);
  gemm_kernel<<<PP / 8, 256, 0, stream>>>(x, W, bias, a, hist);
  thr_kernel<<<1, 1024, 0, stream>>>(a, hist, thr);
  spmv_kernel<<<256, 1024, 0, stream>>>(vals, rows, cols, a, thr, sstate, rec, nc);
  finalize_kernel<<<PP / 256, 256, 0, stream>>>(rec, a, thr, sstate, out, acc);
}

// Round 8
// 90.124 us; speedup vs baseline: 3.7181x; 1.8072x over previous
//
#include <hip/hip_runtime.h>
#include <math.h>

#define PP 8192
#define DD 4096
#define NTOT 32768           // B * P
#define K_LOW 29490          // floor(0.9 * (NTOT-1))
#define NBINS 8192           // bucket = bits(|a|) >> 18
#define SCALE 1048576.0f     // 2^20 fixed-point for spmv accumulation
#define INV_SCALE (1.0f / 1048576.0f)
#define MSCALE 262144.0f     // 2^18 fixed-point for mean-sum accumulation
#define INV_MSCALE (1.0f / 262144.0f)
#define LIST_CAP 3072

__device__ __forceinline__ float dot4(float4 w, float4 v) {
  return fmaf(w.x, v.x, fmaf(w.y, v.y, fmaf(w.z, v.z, w.w * v.w)));
}

// ---------------- Kernel 1: a = x @ W^T + b ----------------
// 2048 blocks x 256 thr, 1 row/wave -> 32 waves/CU for max memory-level
// parallelism (W streams at HBM; x is L1/L2-hot). NO global atomics (R7
// lesson: hot-bin global atomic hist cost ~100us of serialized RMW).
// First 65 blocks zero hist/rec/acc (consumed only by later dispatches).
__global__ __launch_bounds__(256, 8) void gemm_kernel(const float* __restrict__ x,
                                                      const float* __restrict__ W,
                                                      const float* __restrict__ bias,
                                                      float* __restrict__ a,
                                                      unsigned* __restrict__ hist,
                                                      int* __restrict__ rec,
                                                      int* __restrict__ acc) {
  if (blockIdx.x < 32) {
    hist[blockIdx.x * 256 + threadIdx.x] = 0u;
  } else if (blockIdx.x < 64) {
    rec[(blockIdx.x - 32) * 256 + threadIdx.x] = 0;
  } else if (blockIdx.x == 64 && threadIdx.x < 4) {
    acc[threadIdx.x] = 0;
  }
  const int wave = threadIdx.x >> 6;
  const int lane = threadIdx.x & 63;
  const int p = blockIdx.x * 4 + wave;
  const float4* __restrict__ Wr = (const float4*)(W + (size_t)p * DD);
  const float4* __restrict__ x4 = (const float4*)x;
  double a0 = 0.0, a1 = 0.0, a2 = 0.0, a3 = 0.0;
  #pragma unroll 4
  for (int k = 0; k < 16; ++k) {
    const int i = lane + k * 64;
    float4 w  = Wr[i];
    float4 v0 = x4[i];
    float4 v1 = x4[1024 + i];
    float4 v2 = x4[2048 + i];
    float4 v3 = x4[3072 + i];
    a0 += (double)dot4(w, v0);
    a1 += (double)dot4(w, v1);
    a2 += (double)dot4(w, v2);
    a3 += (double)dot4(w, v3);
  }
  #pragma unroll
  for (int off = 32; off > 0; off >>= 1) {
    a0 += __shfl_down(a0, off);
    a1 += __shfl_down(a1, off);
    a2 += __shfl_down(a2, off);
    a3 += __shfl_down(a3, off);
  }
  if (lane == 0) {
    float bp = bias[p];
    a[0 * PP + p] = (float)a0 + bp;
    a[1 * PP + p] = (float)a1 + bp;
    a[2 * PP + p] = (float)a2 + bp;
    a[3 * PP + p] = (float)a3 + bp;
  }
}

// ---------------- Kernel 2: histogram via per-block LDS (native ds_add_u32) ----------------
// 8 blocks x 1024 thr x 4 elems; global merge via spread atomics (<=8 per addr).
__global__ __launch_bounds__(1024) void hist_kernel(const float* __restrict__ a,
                                                    unsigned* __restrict__ hist) {
  __shared__ unsigned h[NBINS];
  const int tid = threadIdx.x;
  #pragma unroll
  for (int j = 0; j < NBINS / 1024; ++j) h[tid + j * 1024] = 0u;
  __syncthreads();
  const int base = blockIdx.x * 4096 + tid;
  #pragma unroll
  for (int k = 0; k < 4; ++k) {
    unsigned u = __float_as_uint(fabsf(a[base + k * 1024]));
    atomicAdd(&h[u >> 18], 1u);
  }
  __syncthreads();
  #pragma unroll
  for (int j = 0; j < NBINS / 1024; ++j) {
    unsigned c = h[tid + j * 1024];
    if (c) atomicAdd(&hist[tid + j * 1024], c);
  }
}

// ---------------- Kernel 3: exact 0.9-quantile from prebuilt histogram ----------------
__global__ __launch_bounds__(1024) void thr_kernel(const float* __restrict__ a,
                                                   const unsigned* __restrict__ hist,
                                                   float* __restrict__ thr) {
  __shared__ unsigned scan[1024];
  __shared__ unsigned list1[LIST_CAP];
  __shared__ unsigned list2[LIST_CAP];
  __shared__ unsigned s_n1, s_n2;
  __shared__ unsigned s_b1, s_r1, s_b2, s_r2;
  __shared__ unsigned s_vlo, s_vhi;
  const int tid = threadIdx.x;
  const uint4* h4 = (const uint4*)hist;
  uint4 q0 = h4[tid * 2];
  uint4 q1 = h4[tid * 2 + 1];
  unsigned part = q0.x + q0.y + q0.z + q0.w + q1.x + q1.y + q1.z + q1.w;
  scan[tid] = part;
  if (tid == 0) { s_n1 = 0; s_n2 = 0; }
  __syncthreads();
  for (int off = 1; off < 1024; off <<= 1) {
    unsigned v = (tid >= off) ? scan[tid - off] : 0u;
    __syncthreads();
    scan[tid] += v;
    __syncthreads();
  }
  const unsigned incl = scan[tid];
  const unsigned excl = incl - part;
  unsigned bins[8] = {q0.x, q0.y, q0.z, q0.w, q1.x, q1.y, q1.z, q1.w};
  if (excl <= (unsigned)K_LOW && (unsigned)K_LOW < incl) {
    unsigned r = (unsigned)K_LOW - excl, cum = 0;
    #pragma unroll
    for (int j = 0; j < 8; ++j) {
      if (cum + bins[j] > r) { s_b1 = tid * 8 + j; s_r1 = r - cum; break; }
      cum += bins[j];
    }
  }
  if (excl <= (unsigned)(K_LOW + 1) && (unsigned)(K_LOW + 1) < incl) {
    unsigned r = (unsigned)(K_LOW + 1) - excl, cum = 0;
    #pragma unroll
    for (int j = 0; j < 8; ++j) {
      if (cum + bins[j] > r) { s_b2 = tid * 8 + j; s_r2 = r - cum; break; }
      cum += bins[j];
    }
  }
  __syncthreads();
  const unsigned b1 = s_b1, r1 = s_r1, b2 = s_b2, r2 = s_r2;
  for (int i = tid; i < NTOT; i += 1024) {
    unsigned u = __float_as_uint(fabsf(a[i]));
    unsigned bk = u >> 18;
    if (bk == b1) {
      unsigned idx = atomicAdd(&s_n1, 1u);
      if (idx < LIST_CAP) list1[idx] = u;
    } else if (bk == b2) {
      unsigned idx = atomicAdd(&s_n2, 1u);
      if (idx < LIST_CAP) list2[idx] = u;
    }
  }
  __syncthreads();
  const unsigned m1 = min(s_n1, (unsigned)LIST_CAP);
  const unsigned m2 = min(s_n2, (unsigned)LIST_CAP);
  for (unsigned i = tid; i < m1; i += 1024) {
    unsigned ui = list1[i];
    unsigned ltc = 0, eqb = 0;
    for (unsigned j = 0; j < m1; ++j) {
      unsigned uj = list1[j];
      ltc += (uj < ui) ? 1u : 0u;
      eqb += ((uj == ui) && (j < i)) ? 1u : 0u;
    }
    unsigned rk = ltc + eqb;
    if (rk == r1) s_vlo = ui;
    if (b2 == b1 && rk == r2) s_vhi = ui;
  }
  if (b2 != b1) {
    for (unsigned i = tid; i < m2; i += 1024) {
      unsigned ui = list2[i];
      unsigned ltc = 0, eqb = 0;
      for (unsigned j = 0; j < m2; ++j) {
        unsigned uj = list2[j];
        ltc += (uj < ui) ? 1u : 0u;
        eqb += ((uj == ui) && (j < i)) ? 1u : 0u;
      }
      if (ltc + eqb == r2) s_vhi = ui;
    }
  }
  __syncthreads();
  if (tid == 0) {
    double dlo = (double)__uint_as_float(s_vlo);
    double dhi = (double)__uint_as_float(s_vhi);
    double idx = 0.9 * (double)(NTOT - 1);
    double g = idx - floor(idx);
    thr[0] = (float)(dlo + g * (dhi - dlo));
  }
}

// ---------------- Kernel 4: COO SpMV, int fixed-point LDS accum ----------------
__global__ __launch_bounds__(1024) void spmv_kernel(const float* __restrict__ vals,
                                                    const int* __restrict__ rows,
                                                    const int* __restrict__ cols,
                                                    const float* __restrict__ a,
                                                    const float* __restrict__ thr,
                                                    const float* __restrict__ sstate,
                                                    int* __restrict__ rec,
                                                    int nc) {
  __shared__ float s_state[PP];
  __shared__ int s_rec[PP];
  const int tid = threadIdx.x;
  const float t = thr[0];
  for (int i = tid; i < PP; i += 1024) {
    float a0 = a[i];
    s_state[i] = (fabsf(a0) > t) ? a0 : 0.9f * sstate[i];
    s_rec[i] = 0;
  }
  __syncthreads();
  const int n4 = nc >> 2;
  const int stride = gridDim.x * 1024;
  const float4* __restrict__ v4 = (const float4*)vals;
  const int4* __restrict__ r4 = (const int4*)rows;
  const int4* __restrict__ c4 = (const int4*)cols;
  for (int i = blockIdx.x * 1024 + tid; i < n4; i += stride) {
    float4 v = v4[i];
    int4 r = r4[i];
    int4 c = c4[i];
    atomicAdd((unsigned*)&s_rec[r.x], (unsigned)__float2int_rn(v.x * s_state[c.x] * SCALE));
    atomicAdd((unsigned*)&s_rec[r.y], (unsigned)__float2int_rn(v.y * s_state[c.y] * SCALE));
    atomicAdd((unsigned*)&s_rec[r.z], (unsigned)__float2int_rn(v.z * s_state[c.z] * SCALE));
    atomicAdd((unsigned*)&s_rec[r.w], (unsigned)__float2int_rn(v.w * s_state[c.w] * SCALE));
  }
  if (blockIdx.x == 0 && tid < (nc - (n4 << 2))) {
    int i = (n4 << 2) + tid;
    atomicAdd((unsigned*)&s_rec[rows[i]],
              (unsigned)__float2int_rn(vals[i] * s_state[cols[i]] * SCALE));
  }
  __syncthreads();
  for (int i = tid; i < PP; i += 1024)
    atomicAdd((unsigned*)&rec[i], (unsigned)s_rec[i]);
}

// ---------------- Kernel 5: GELU + fused scalars (last-block completion) ----------------
__global__ __launch_bounds__(256) void finalize_kernel(const int* __restrict__ rec,
                                                       const float* __restrict__ a,
                                                       const float* __restrict__ thr,
                                                       const float* __restrict__ sstate,
                                                       float* __restrict__ out,
                                                       int* __restrict__ acc) {
  __shared__ float wsum[4];
  __shared__ unsigned wcnt[4];
  const int p = blockIdx.x * 256 + threadIdx.x;
  const float t = thr[0];
  float r = (float)rec[p] * INV_SCALE;
  float a0 = a[p];
  bool m = fabsf(a0) > t;
  float st = m ? a0 : 0.9f * sstate[p];
  float v = st + 0.1f * r;
  float ns = 0.5f * v * (1.0f + erff(v * 0.70710678118654752440f));
  out[p] = ns;
  float lsum = m ? ns : 0.0f;
  unsigned lcnt = m ? 1u : 0u;
  #pragma unroll
  for (int off = 32; off > 0; off >>= 1) {
    lsum += __shfl_down(lsum, off);
    lcnt += __shfl_down(lcnt, off);
  }
  const int lane = threadIdx.x & 63;
  const int wid = threadIdx.x >> 6;
  if (lane == 0) { wsum[wid] = lsum; wcnt[wid] = lcnt; }
  __syncthreads();
  if (threadIdx.x == 0) {
    float bsum = wsum[0] + wsum[1] + wsum[2] + wsum[3];
    unsigned bcnt = wcnt[0] + wcnt[1] + wcnt[2] + wcnt[3];
    atomicAdd((unsigned*)&acc[0], (unsigned)__float2int_rn(bsum * MSCALE));
    atomicAdd((unsigned*)&acc[1], bcnt);
    __threadfence();
    unsigned d = atomicAdd((unsigned*)&acc[2], 1u);
    if (d == (unsigned)(gridDim.x - 1)) {
      int sfix = (int)atomicAdd((unsigned*)&acc[0], 0u);
      int cnt = (int)atomicAdd((unsigned*)&acc[1], 0u);
      out[PP] = (float)cnt;
      out[PP + 1] = (cnt > 0) ? ((float)sfix * INV_MSCALE / (float)cnt) : 0.0f;
    }
  }
}

extern "C" void kernel_launch(void* const* d_in, const int* in_sizes, int n_in,
                              void* d_out, int out_size, void* d_ws, size_t ws_size,
                              hipStream_t stream) {
  const float* x      = (const float*)d_in[0];
  const float* W      = (const float*)d_in[1];
  const float* bias   = (const float*)d_in[2];
  const float* vals   = (const float*)d_in[3];
  const float* sstate = (const float*)d_in[4];
  const int*   rows   = (const int*)d_in[5];
  const int*   cols   = (const int*)d_in[6];
  const int    nc     = in_sizes[3];
  float* out = (float*)d_out;
  float* ws  = (float*)d_ws;

  float*    a    = ws;                              // 32768 floats
  float*    thr  = ws + 32768;                      // 16 floats
  unsigned* hist = (unsigned*)(ws + 32784);         // 8192 bins
  int*      rec  = (int*)(ws + 32784 + NBINS);      // 8192 ints
  int*      acc  = (int*)(ws + 32784 + NBINS + PP); // 4 ints

  gemm_kernel<<<PP / 4, 256, 0, stream>>>(x, W, bias, a, hist, rec, acc);
  hist_kernel<<<NTOT / 4096, 1024, 0, stream>>>(a, hist);
  thr_kernel<<<1, 1024, 0, stream>>>(a, hist, thr);
  spmv_kernel<<<256, 1024, 0, stream>>>(vals, rows, cols, a, thr, sstate, rec, nc);
  finalize_kernel<<<PP / 256, 256, 0, stream>>>(rec, a, thr, sstate, out, acc);
}